// Round 5
// baseline (209.730 us; speedup 1.0000x reference)
//
#include <hip/hip_runtime.h>
#include <hip/hip_bf16.h>
#include <stdint.h>

#define BATCH 4
#define L_SEQ 2048
#define DIM   1024

typedef __bf16 bf16;
typedef __bf16 bf16x4 __attribute__((ext_vector_type(4)));
typedef __bf16 bf16x8 __attribute__((ext_vector_type(8)));
typedef float  f32x4  __attribute__((ext_vector_type(4)));

#define GLDS(src, dst) __builtin_amdgcn_global_load_lds(\
    (const __attribute__((address_space(1))) void*)(src), \
    (__attribute__((address_space(3))) void*)(dst), 16, 0, 0)

#define BAR() do { __builtin_amdgcn_sched_barrier(0); \
                   asm volatile("" ::: "memory"); \
                   __builtin_amdgcn_s_barrier(); \
                   asm volatile("" ::: "memory"); \
                   __builtin_amdgcn_sched_barrier(0); } while (0)

#define MFMA16 __builtin_amdgcn_mfma_f32_16x16x32_bf16

// ---------------- fp32 -> bf16 convert (vectorized x4) ----------------
__global__ __launch_bounds__(256)
void cvt_f32_bf16(const float* __restrict__ in, bf16* __restrict__ out, int n4)
{
    int i = blockIdx.x * 256 + threadIdx.x;
    if (i >= n4) return;
    float4 v = ((const float4*)in)[i];
    bf16x4 o = { (bf16)v.x, (bf16)v.y, (bf16)v.z, (bf16)v.w };
    ((bf16x4*)out)[i] = o;
}

// ---- 256x256-tile, BK=64, 8 waves, 8-phase counted-vmcnt bf16 MFMA GEMM ----
// A[m][k], B[n][k], K-contiguous.  C = A * B^T, fp32 accum. A = the operand
// whose dim is contiguous in the output (D frag = 4 consecutive M rows).
// MODE 0: QKV  A=Wcat[3072][1024], B=X[8192][1024]; Q/K -> [l][e] bf16 +bias, V -> Vt[e][l] +bias
// MODE 2: SC   A=K[2048][1024],    B=Q[2048][1024]; wts[q][k] f32 *1/32; upper tiles zero-filled
// MODE 3: PV   A=Vt[1024][2048],   B=P[2048][2048]; out[q][e] f32; causal K truncation
template<int MODE>
__global__ __launch_bounds__(512, 2)
void gemm8p(const bf16* __restrict__ Abase, const bf16* __restrict__ Bbase,
            const float* __restrict__ bqp, const float* __restrict__ bkp,
            const float* __restrict__ bvp,
            void* __restrict__ o0, void* __restrict__ o1, void* __restrict__ o2)
{
    // 8 half-tile slots x 16 KiB ([128 rows][64 cols] bf16) = 128 KiB
    // slot(parity,op,half) = ((parity*4) + op*2 + half) * 16384
    __shared__ __align__(16) char smem[131072];

    const int z = blockIdx.z;
    int m0, n0;
    const bf16 *Aop, *Bop;
    int lda, ldb, nt;

    if constexpr (MODE == 0) {
        m0 = blockIdx.x * 256; n0 = blockIdx.y * 256;
        Aop = Abase; Bop = Bbase; lda = DIM; ldb = DIM; nt = 16;
    } else if constexpr (MODE == 2) {
        const int u = blockIdx.x;
        if (u >= 36) {                            // strict-upper (k>q) tile: zeros only
            int v = u - 36;
            int mi = 1; while (mi * (mi + 1) / 2 <= v) ++mi;
            int ni = v - mi * (mi - 1) / 2;       // mi > ni
            float* sc = (float*)o0 + (size_t)z * L_SEQ * L_SEQ;
            const int row = ni * 256 + (threadIdx.x >> 1);
            float* p = sc + (size_t)row * L_SEQ + mi * 256 + (threadIdx.x & 1) * 128;
            f32x4 z4 = {0.f, 0.f, 0.f, 0.f};
#pragma unroll
            for (int c = 0; c < 32; ++c) *(f32x4*)(p + c * 4) = z4;
            return;
        }
        int ni = 0; while ((ni + 1) * (ni + 2) / 2 <= u) ++ni;
        int mi = u - ni * (ni + 1) / 2;           // mi <= ni  (k-tile <= q-tile)
        m0 = mi * 256; n0 = ni * 256;
        Aop = Abase + (size_t)z * L_SEQ * DIM;    // K
        Bop = Bbase + (size_t)z * L_SEQ * DIM;    // Q
        lda = DIM; ldb = DIM; nt = 16;
    } else {
        m0 = blockIdx.x * 256; n0 = blockIdx.y * 256;
        Aop = Abase + (size_t)z * DIM * L_SEQ;    // Vt
        Bop = Bbase + (size_t)z * L_SEQ * L_SEQ;  // P
        lda = L_SEQ; ldb = L_SEQ; nt = (n0 >> 6) + 4;   // k < n0+256 (P zero beyond)
    }

    const int tid  = threadIdx.x;
    const int w    = tid >> 6, lane = tid & 63;
    const int wm   = w >> 2, wn = w & 3;          // 2 (M) x 4 (N) waves
    const int l15  = lane & 15, lh = lane >> 4;
    const int lr4  = lh << 2;

    // ---- staging geometry: linear LDS dest, inverse-swizzled global src ----
    const int p0 = (w * 2 + 0) * 1024 + lane * 16;
    const int p1 = (w * 2 + 1) * 1024 + lane * 16;
    const int Ls0 = p0 ^ (((p0 >> 7) & 7) << 4);
    const int Ls1 = p1 ^ (((p1 >> 7) & 7) << 4);
    const int sr0 = Ls0 >> 7, sc0 = (Ls0 & 127) >> 1;
    const int sr1 = Ls1 >> 7, sc1 = (Ls1 & 127) >> 1;

    auto stage = [&](int t, int op, int half) {
        const bf16* ob = op ? Bop : Aop;
        const int  ld  = op ? ldb : lda;
        const int  r0  = (op ? n0 : m0) + half * 128;
        const int  k0  = t << 6;
        char* base = smem + (((t & 1) * 4 + op * 2 + half) * 16384);
        GLDS(ob + (size_t)(r0 + sr0) * ld + (k0 + sc0), base + (w * 2 + 0) * 1024);
        GLDS(ob + (size_t)(r0 + sr1) * ld + (k0 + sc1), base + (w * 2 + 1) * 1024);
    };

    // ---- fragment-read addressing (XOR-swizzled) ----
    const int swz = (l15 & 7) << 4;
    const int ko0 = (lh << 4) ^ swz;              // kk=0 byte offset within row
    const int ko1 = (64 + (lh << 4)) ^ swz;       // kk=1
    const int rB  = (wn & 1) * 64;                // row base within this wave's B half

    f32x4 acc[8][4];
#pragma unroll
    for (int i = 0; i < 8; ++i)
#pragma unroll
        for (int j = 0; j < 4; ++j) acc[i][j] = (f32x4){0.f, 0.f, 0.f, 0.f};

    // ---- prologue: tiles 0 and 1 fully staged; tile 0 resident, tile 1 in flight ----
    stage(0, 0, 0); stage(0, 0, 1); stage(0, 1, 0); stage(0, 1, 1);
    stage(1, 0, 0); stage(1, 0, 1); stage(1, 1, 0); stage(1, 1, 1);
    asm volatile("s_waitcnt vmcnt(8)" ::: "memory");
    __builtin_amdgcn_s_barrier();
    asm volatile("" ::: "memory");

    auto ktile = [&](int t, int buf) {
        char* baseA = smem + ((buf * 4 + wm) * 16384);
        char* baseB = smem + ((buf * 4 + 2 + (wn >> 1)) * 16384);
        bf16x8 af[4][2], bfr[4][2];
        const bool pref = (t + 2 < nt);

        // ---- q0: A rows 0-63 + B cols 0-31 ----
#pragma unroll
        for (int i = 0; i < 4; ++i) {
            int ro = (i * 16 + l15) * 128;
            af[i][0] = *(const bf16x8*)(baseA + ro + ko0);
            af[i][1] = *(const bf16x8*)(baseA + ro + ko1);
        }
#pragma unroll
        for (int j = 0; j < 2; ++j) {
            int ro = (rB + j * 16 + l15) * 128;
            bfr[j][0] = *(const bf16x8*)(baseB + ro + ko0);
            bfr[j][1] = *(const bf16x8*)(baseB + ro + ko1);
        }
        BAR();
        __builtin_amdgcn_s_setprio(1);
#pragma unroll
        for (int i = 0; i < 4; ++i)
#pragma unroll
            for (int j = 0; j < 2; ++j) {
                acc[i][j] = MFMA16(af[i][0], bfr[j][0], acc[i][j], 0, 0, 0);
                acc[i][j] = MFMA16(af[i][1], bfr[j][1], acc[i][j], 0, 0, 0);
            }
        __builtin_amdgcn_s_setprio(0);
        BAR();

        // ---- q1: B cols 32-63 ----
#pragma unroll
        for (int j = 0; j < 2; ++j) {
            int ro = (rB + (j + 2) * 16 + l15) * 128;
            bfr[j + 2][0] = *(const bf16x8*)(baseB + ro + ko0);
            bfr[j + 2][1] = *(const bf16x8*)(baseB + ro + ko1);
        }
        BAR();
        __builtin_amdgcn_s_setprio(1);
#pragma unroll
        for (int i = 0; i < 4; ++i)
#pragma unroll
            for (int j = 0; j < 2; ++j) {
                acc[i][j + 2] = MFMA16(af[i][0], bfr[j + 2][0], acc[i][j + 2], 0, 0, 0);
                acc[i][j + 2] = MFMA16(af[i][1], bfr[j + 2][1], acc[i][j + 2], 0, 0, 0);
            }
        __builtin_amdgcn_s_setprio(0);
        BAR();

        // ---- q2: A rows 64-127 (af03 dead); stage t+2 B halves (B freed after q1) ----
#pragma unroll
        for (int i = 0; i < 4; ++i) {
            int ro = ((i + 4) * 16 + l15) * 128;
            af[i][0] = *(const bf16x8*)(baseA + ro + ko0);
            af[i][1] = *(const bf16x8*)(baseA + ro + ko1);
        }
        if (pref) { stage(t + 2, 1, 0); stage(t + 2, 1, 1); }
        BAR();
        __builtin_amdgcn_s_setprio(1);
#pragma unroll
        for (int i = 0; i < 4; ++i)
#pragma unroll
            for (int j = 0; j < 2; ++j) {
                acc[i + 4][j + 2] = MFMA16(af[i][0], bfr[j + 2][0], acc[i + 4][j + 2], 0, 0, 0);
                acc[i + 4][j + 2] = MFMA16(af[i][1], bfr[j + 2][1], acc[i + 4][j + 2], 0, 0, 0);
            }
        __builtin_amdgcn_s_setprio(0);
        BAR();

        // ---- q3: stage t+2 A halves (A freed after q2); tile boundary ----
        if (pref) { stage(t + 2, 0, 0); stage(t + 2, 0, 1); }
        BAR();
        __builtin_amdgcn_s_setprio(1);
#pragma unroll
        for (int i = 0; i < 4; ++i)
#pragma unroll
            for (int j = 0; j < 2; ++j) {
                acc[i + 4][j] = MFMA16(af[i][0], bfr[j][0], acc[i + 4][j], 0, 0, 0);
                acc[i + 4][j] = MFMA16(af[i][1], bfr[j][1], acc[i + 4][j], 0, 0, 0);
            }
        __builtin_amdgcn_s_setprio(0);
        if (pref) {
            asm volatile("s_waitcnt vmcnt(8)" ::: "memory");  // t+1 resident; t+2's 4 HTs in flight
        } else if (t + 1 < nt) {
            asm volatile("s_waitcnt vmcnt(0)" ::: "memory");  // final prefetch drained
        }
        BAR();
    };

    for (int t = 0; t < nt; t += 2) { ktile(t, 0); ktile(t + 1, 1); }

    // ---- epilogue: D frag = 4 consecutive M rows (lh*4+r), N col = l15 ----
    if constexpr (MODE == 0) {
        const int sel = m0 >> 10;                 // 0:Q 1:K 2:V (uniform per block)
        const int eb  = (m0 & 1023) + wm * 128;
        if (sel < 2) {
            bf16* out = sel == 0 ? (bf16*)o0 : (bf16*)o1;
            const float* bias = sel == 0 ? bqp : bkp;
#pragma unroll
            for (int i = 0; i < 8; ++i) {
                int e0 = eb + i * 16 + lr4;
                float4 bb = *(const float4*)(bias + e0);
#pragma unroll
                for (int j = 0; j < 4; ++j) {
                    int l = n0 + wn * 64 + j * 16 + l15;
                    bf16x4 v = { (bf16)(acc[i][j][0] + bb.x), (bf16)(acc[i][j][1] + bb.y),
                                 (bf16)(acc[i][j][2] + bb.z), (bf16)(acc[i][j][3] + bb.w) };
                    *(bf16x4*)((bf16*)out + (size_t)l * DIM + e0) = v;
                }
            }
        } else {
            bf16* Vt = (bf16*)o2;
#pragma unroll
            for (int i = 0; i < 8; ++i) {
                int e0 = eb + i * 16 + lr4;
                float4 bb = *(const float4*)(bvp + e0);
                float bbr[4] = { bb.x, bb.y, bb.z, bb.w };
#pragma unroll
                for (int j = 0; j < 4; ++j) {
                    int lg = n0 + wn * 64 + j * 16 + l15;
                    int b = lg >> 11, l = lg & 2047;
#pragma unroll
                    for (int r = 0; r < 4; ++r)
                        Vt[((size_t)b * DIM + e0 + r) * L_SEQ + l] = (bf16)(acc[i][j][r] + bbr[r]);
                }
            }
        }
    } else if constexpr (MODE == 2) {
        float* sc = (float*)o0 + (size_t)z * L_SEQ * L_SEQ;
#pragma unroll
        for (int i = 0; i < 8; ++i) {
            int k0e = m0 + wm * 128 + i * 16 + lr4;
#pragma unroll
            for (int j = 0; j < 4; ++j) {
                int q = n0 + wn * 64 + j * 16 + l15;
                f32x4 v = acc[i][j] * 0.03125f;
                *(f32x4*)(sc + (size_t)q * L_SEQ + k0e) = v;
            }
        }
    } else {
        float* o = (float*)o0 + (size_t)z * L_SEQ * DIM;
#pragma unroll
        for (int i = 0; i < 8; ++i) {
            int e0 = m0 + wm * 128 + i * 16 + lr4;
#pragma unroll
            for (int j = 0; j < 4; ++j) {
                int q = n0 + wn * 64 + j * 16 + l15;
                *(f32x4*)(o + (size_t)q * DIM + e0) = acc[i][j];
            }
        }
    }
}

// ---------------- causal row softmax: wts fp32 (in-place) + bf16 copy ----------------
__global__ __launch_bounds__(256)
void softmax_rows(float* __restrict__ wts, bf16* __restrict__ Pb)
{
    const int row = blockIdx.x;                 // 0..8191
    const int q = row & 2047;
    float* s = wts + (size_t)row * L_SEQ;
    bf16*  p = Pb  + (size_t)row * L_SEQ;
    const int t = threadIdx.x;
    const int lane = t & 63, w = t >> 6;
    const int k0 = t * 8;

    float v[8];
    if (k0 + 7 <= q) {
        float4 a = *(const float4*)(s + k0);
        float4 b = *(const float4*)(s + k0 + 4);
        v[0]=a.x; v[1]=a.y; v[2]=a.z; v[3]=a.w;
        v[4]=b.x; v[5]=b.y; v[6]=b.z; v[7]=b.w;
    } else {
#pragma unroll
        for (int c = 0; c < 8; ++c) {
            int k = k0 + c;
            v[c] = (k <= q) ? s[k] : -3.0e38f;
        }
    }

    float mx = v[0];
#pragma unroll
    for (int c = 1; c < 8; ++c) mx = fmaxf(mx, v[c]);
#pragma unroll
    for (int off = 32; off; off >>= 1) mx = fmaxf(mx, __shfl_xor(mx, off));
    __shared__ float redm[4];
    if (lane == 0) redm[w] = mx;
    __syncthreads();
    mx = fmaxf(fmaxf(redm[0], redm[1]), fmaxf(redm[2], redm[3]));

    float sm = 0.f;
#pragma unroll
    for (int c = 0; c < 8; ++c) {
        float e = __expf(v[c] - mx);             // masked -> 0 exactly
        v[c] = e;
        sm += e;
    }
#pragma unroll
    for (int off = 32; off; off >>= 1) sm += __shfl_xor(sm, off);
    __shared__ float reds[4];
    if (lane == 0) reds[w] = sm;
    __syncthreads();
    sm = reds[0] + reds[1] + reds[2] + reds[3];
    const float inv = 1.f / sm;

    if (k0 <= (q | 255)) {                       // beyond diag tile: pre-zeroed, PV never reads
        float o[8];
#pragma unroll
        for (int c = 0; c < 8; ++c) o[c] = v[c] * inv;
        float4 s0 = { o[0], o[1], o[2], o[3] };
        float4 s1 = { o[4], o[5], o[6], o[7] };
        *(float4*)(s + k0)     = s0;
        *(float4*)(s + k0 + 4) = s1;
        bf16x8 pb = { (bf16)o[0], (bf16)o[1], (bf16)o[2], (bf16)o[3],
                      (bf16)o[4], (bf16)o[5], (bf16)o[6], (bf16)o[7] };
        *(bf16x8*)(p + k0) = pb;
    }
}

extern "C" void kernel_launch(void* const* d_in, const int* in_sizes, int n_in,
                              void* d_out, int out_size, void* d_ws, size_t ws_size,
                              hipStream_t stream)
{
    const float* x  = (const float*)d_in[0];
    const float* Wq = (const float*)d_in[1];
    const float* bq = (const float*)d_in[2];
    const float* Wk = (const float*)d_in[3];
    const float* bk = (const float*)d_in[4];
    const float* Wv = (const float*)d_in[5];
    const float* bv = (const float*)d_in[6];

    float* out = (float*)d_out;                               // [4][2048][1024]
    float* wts = out + (size_t)BATCH * L_SEQ * DIM;           // [4][2048][2048]

    char* ws = (char*)d_ws;
    bf16* Xb   = (bf16*)(ws + 0);                  // 16 MiB  [8192][1024]
    bf16* Wcat = (bf16*)(ws + (16u  << 20));       //  6 MiB  [3072][1024]  (Wq;Wk;Wv)
    bf16* Qb   = (bf16*)(ws + (22u  << 20));       // 16 MiB  [b][l][e]
    bf16* Kb   = (bf16*)(ws + (38u  << 20));       // 16 MiB  [b][l][e]
    bf16* Vt   = (bf16*)(ws + (54u  << 20));       // 16 MiB  [b][e][l]
    bf16* Pb   = (bf16*)(ws + (70u  << 20));       // 32 MiB  [b][q][k]

    cvt_f32_bf16<<<dim3(8192), dim3(256), 0, stream>>>(x,  Xb, 8388608 / 4);
    cvt_f32_bf16<<<dim3(1024), dim3(256), 0, stream>>>(Wq, Wcat,           1048576 / 4);
    cvt_f32_bf16<<<dim3(1024), dim3(256), 0, stream>>>(Wk, Wcat + 1048576, 1048576 / 4);
    cvt_f32_bf16<<<dim3(1024), dim3(256), 0, stream>>>(Wv, Wcat + 2097152, 1048576 / 4);

    gemm8p<0><<<dim3(12, 32, 1), dim3(512), 0, stream>>>(Wcat, Xb, bq, bk, bv, Qb, Kb, Vt);
    gemm8p<2><<<dim3(64, 1, 4),  dim3(512), 0, stream>>>(Kb, Qb, nullptr, nullptr, nullptr, wts, nullptr, nullptr);
    softmax_rows<<<dim3(8192), dim3(256), 0, stream>>>(wts, Pb);
    gemm8p<3><<<dim3(4, 8, 4),   dim3(512), 0, stream>>>(Vt, Pb, nullptr, nullptr, nullptr, out, nullptr, nullptr);
}

// Round 6
// 178.777 us; speedup vs baseline: 1.1731x; 1.1731x over previous
//
#include <hip/hip_runtime.h>
#include <hip/hip_bf16.h>
#include <stdint.h>

#define BATCH 4
#define L_SEQ 2048
#define DIM   1024

typedef __bf16 bf16;
typedef __bf16 bf16x4 __attribute__((ext_vector_type(4)));
typedef __bf16 bf16x8 __attribute__((ext_vector_type(8)));
typedef float  f32x4  __attribute__((ext_vector_type(4)));

#define GLDS(src, dst) __builtin_amdgcn_global_load_lds(\
    (const __attribute__((address_space(1))) void*)(src), \
    (__attribute__((address_space(3))) void*)(dst), 16, 0, 0)

// barrier WITHOUT sched_barrier(0): memory ops can't cross (clobber), but the
// scheduler stays free to place fine-grained per-use lgkmcnt waits (m141 lesson).
#define BARX() do { asm volatile("" ::: "memory"); \
                    __builtin_amdgcn_s_barrier(); \
                    asm volatile("" ::: "memory"); } while (0)

#define MFMA16 __builtin_amdgcn_mfma_f32_16x16x32_bf16

// ---------------- fused fp32 -> bf16 convert (x + Wq + Wk + Wv) ----------------
__global__ __launch_bounds__(256)
void cvt_all(const float* __restrict__ x,  const float* __restrict__ Wq,
             const float* __restrict__ Wk, const float* __restrict__ Wv,
             bf16* __restrict__ Xb, bf16* __restrict__ Wcat)
{
    const int b = blockIdx.x;
    const float* src; bf16* dst; int i;
    if (b < 8192) { src = x; dst = Xb; i = b * 256 + threadIdx.x; }
    else {
        int s = (b - 8192) >> 10;
        src = s == 0 ? Wq : (s == 1 ? Wk : Wv);
        dst = Wcat + (size_t)s * 1048576;
        i = ((b - 8192) & 1023) * 256 + threadIdx.x;
    }
    float4 v = ((const float4*)src)[i];
    bf16x4 o = { (bf16)v.x, (bf16)v.y, (bf16)v.z, (bf16)v.w };
    ((bf16x4*)dst)[i] = o;
}

// ---- generalized BMxBN-tile, BK=64, 8-phase counted-vmcnt bf16 MFMA GEMM ----
// A[m][k], B[n][k], K-contiguous.  C = A * B^T, fp32 accum. A = operand whose
// dim is contiguous in the output (D frag = 4 consecutive M rows).
// MODE 0: QKV  A=Wcat[3072][1024], B=X[8192][1024]; 256x256, XCD-chunked grid
// MODE 2: SC   A=K[2048][1024],    B=Q[2048][1024]; 128x256, causal decode + zero-fill
// MODE 3: PV   A=Vt[1024][2048],   B=P[2048][2048]; 128x128, heavy-first, causal nt
template<int MODE, int BM, int BN, int NTH, int WM, int WN>
__global__ __launch_bounds__(NTH, 2)
void gemmX(const bf16* __restrict__ Abase, const bf16* __restrict__ Bbase,
           const float* __restrict__ bqp, const float* __restrict__ bkp,
           const float* __restrict__ bvp,
           void* __restrict__ o0, void* __restrict__ o1, void* __restrict__ o2)
{
    constexpr int MI  = BM / WM / 16;          // A frags per wave (8 or 4)
    constexpr int ASZ = BM * 128;              // bytes per A K-tile
    constexpr int BSZ = BN * 128;
    constexpr int PST = ASZ + BSZ;             // parity stride
    constexpr int SA  = ASZ / (NTH * 16);      // stage steps (1 GLDS/wave each)
    constexpr int SB  = BSZ / (NTH * 16);
    constexpr int SAB = SA + SB;
    static_assert(BN / WN / 16 == 4, "NJ must be 4");

    __shared__ __align__(16) char smem[2 * PST];

    int m0, n0, nt, z = blockIdx.z;
    const bf16 *Aop, *Bop;
    int lda, ldb;

    if constexpr (MODE == 0) {
        // bijective XCD 2D chunk: 8 XCDs as 2(m) x 4(n); 48 blocks/XCD as 6m x 8n
        const int id = blockIdx.x;
        const int xcd = id & 7, i = id >> 3;
        const int mi = (xcd & 1) * 6 + i % 6;   // 0..11
        const int ni = (xcd >> 1) * 8 + i / 6;  // 0..31
        m0 = mi * 256; n0 = ni * 256; nt = 16;
        Aop = Abase; Bop = Bbase; lda = DIM; ldb = DIM;
    } else if constexpr (MODE == 2) {
        const int u = blockIdx.x;
        if (u >= 72) {                           // zero-fill tile (k > q region)
            int v = u - 72, qi = 0;
            while (v >= 14 - 2 * qi) { v -= 14 - 2 * qi; ++qi; }
            const int ki = 2 * qi + 2 + v;
            float* sc = (float*)o0 + (size_t)z * L_SEQ * L_SEQ;
            const int row = qi * 256 + (threadIdx.x >> 1);
            float* p = sc + (size_t)row * L_SEQ + ki * 128 + (threadIdx.x & 1) * 64;
            f32x4 z4 = {0.f, 0.f, 0.f, 0.f};
#pragma unroll
            for (int c = 0; c < 16; ++c) *(f32x4*)(p + c * 4) = z4;
            return;
        }
        int qi = 0;                              // compute tile: u = qi*(qi+1) + ki
        while ((qi + 1) * (qi + 2) <= u) ++qi;
        const int ki = u - qi * (qi + 1);        // 0 .. 2qi+1
        m0 = ki * 128; n0 = qi * 256; nt = 16;
        Aop = Abase + (size_t)z * L_SEQ * DIM;   // K
        Bop = Bbase + (size_t)z * L_SEQ * DIM;   // Q
        lda = DIM; ldb = DIM;
    } else {
        const int id = blockIdx.x;               // 512 flat, heavy-first
        const int qi = 15 - (id >> 5);
        const int ei = (id >> 2) & 7;
        z = id & 3;
        m0 = ei * 128; n0 = qi * 128; nt = 2 * qi + 2;
        Aop = Abase + (size_t)z * DIM * L_SEQ;   // Vt
        Bop = Bbase + (size_t)z * L_SEQ * L_SEQ; // P
        lda = L_SEQ; ldb = L_SEQ;
    }

    const int tid  = threadIdx.x;
    const int w    = tid >> 6, lane = tid & 63;
    const int wm   = w / WN, wn = w % WN;
    const int l15  = lane & 15, lh = lane >> 4;
    const int lr4  = lh << 2;

    // staging: linear LDS dest, inverse-swizzled global source (rule 21)
    auto stageA = [&](int t, int s) {
        const int p = s * (NTH * 16) + tid * 16;
        const int L = p ^ (((p >> 7) & 7) << 4);
        GLDS(Aop + (size_t)(m0 + (p >> 7)) * lda + ((t << 6) + ((L & 127) >> 1)),
             smem + (t & 1) * PST + (p - (lane << 4)));
    };
    auto stageB = [&](int t, int s) {
        const int p = s * (NTH * 16) + tid * 16;
        const int L = p ^ (((p >> 7) & 7) << 4);
        GLDS(Bop + (size_t)(n0 + (p >> 7)) * ldb + ((t << 6) + ((L & 127) >> 1)),
             smem + (t & 1) * PST + ASZ + (p - (lane << 4)));
    };

    // fragment reads: XOR-swizzled (row&7)<<4 on 128-B rows
    const int swz = (l15 & 7) << 4;
    const int ko0 = (lh << 4) ^ swz;
    const int ko1 = (64 + (lh << 4)) ^ swz;
    const int arb = (wm * (BM / 2)) * 128;       // wave A row-block byte base
    const int brb = ASZ + (wn * 64) * 128;       // wave B row-block byte base

    f32x4 acc[MI][4];
#pragma unroll
    for (int i = 0; i < MI; ++i)
#pragma unroll
        for (int j = 0; j < 4; ++j) acc[i][j] = (f32x4){0.f, 0.f, 0.f, 0.f};

#define VMW() do { if constexpr (SAB == 8) asm volatile("s_waitcnt vmcnt(8)" ::: "memory"); \
                   else asm volatile("s_waitcnt vmcnt(6)" ::: "memory"); } while (0)

    // prologue: tiles 0 & 1 staged; wait tile 0 landed (tile 1 in flight)
#pragma unroll
    for (int s = 0; s < SA; ++s) stageA(0, s);
#pragma unroll
    for (int s = 0; s < SB; ++s) stageB(0, s);
#pragma unroll
    for (int s = 0; s < SA; ++s) stageA(1, s);
#pragma unroll
    for (int s = 0; s < SB; ++s) stageB(1, s);
    VMW();
    BARX();

    auto ktile = [&](int t) {
        const bool pref = (t + 2 < nt);
        char* base = smem + (t & 1) * PST;
        bf16x8 af[MI / 2][2], bfr[4][2];

        // q0: A lower half + B cols 0-31
#pragma unroll
        for (int i = 0; i < MI / 2; ++i) {
            int ro = arb + (i * 16 + l15) * 128;
            af[i][0] = *(const bf16x8*)(base + ro + ko0);
            af[i][1] = *(const bf16x8*)(base + ro + ko1);
        }
#pragma unroll
        for (int j = 0; j < 2; ++j) {
            int ro = brb + (j * 16 + l15) * 128;
            bfr[j][0] = *(const bf16x8*)(base + ro + ko0);
            bfr[j][1] = *(const bf16x8*)(base + ro + ko1);
        }
        BARX();
        __builtin_amdgcn_s_setprio(1);
#pragma unroll
        for (int i = 0; i < MI / 2; ++i)
#pragma unroll
            for (int j = 0; j < 2; ++j) {
                acc[i][j] = MFMA16(af[i][0], bfr[j][0], acc[i][j], 0, 0, 0);
                acc[i][j] = MFMA16(af[i][1], bfr[j][1], acc[i][j], 0, 0, 0);
            }
        __builtin_amdgcn_s_setprio(0);
        BARX();

        // q1: B cols 32-63
#pragma unroll
        for (int j = 0; j < 2; ++j) {
            int ro = brb + ((j + 2) * 16 + l15) * 128;
            bfr[j + 2][0] = *(const bf16x8*)(base + ro + ko0);
            bfr[j + 2][1] = *(const bf16x8*)(base + ro + ko1);
        }
        BARX();
        __builtin_amdgcn_s_setprio(1);
#pragma unroll
        for (int i = 0; i < MI / 2; ++i)
#pragma unroll
            for (int j = 0; j < 2; ++j) {
                acc[i][j + 2] = MFMA16(af[i][0], bfr[j + 2][0], acc[i][j + 2], 0, 0, 0);
                acc[i][j + 2] = MFMA16(af[i][1], bfr[j + 2][1], acc[i][j + 2], 0, 0, 0);
            }
        __builtin_amdgcn_s_setprio(0);
        BARX();

        // q2: A upper half; stage t+2 B (B reads done in q0/q1)
#pragma unroll
        for (int i = 0; i < MI / 2; ++i) {
            int ro = arb + ((MI / 2 + i) * 16 + l15) * 128;
            af[i][0] = *(const bf16x8*)(base + ro + ko0);
            af[i][1] = *(const bf16x8*)(base + ro + ko1);
        }
        if (pref) {
#pragma unroll
            for (int s = 0; s < SB; ++s) stageB(t + 2, s);
        }
        BARX();
        __builtin_amdgcn_s_setprio(1);
#pragma unroll
        for (int i = 0; i < MI / 2; ++i)
#pragma unroll
            for (int j = 0; j < 2; ++j) {
                acc[MI / 2 + i][j + 2] = MFMA16(af[i][0], bfr[j + 2][0], acc[MI / 2 + i][j + 2], 0, 0, 0);
                acc[MI / 2 + i][j + 2] = MFMA16(af[i][1], bfr[j + 2][1], acc[MI / 2 + i][j + 2], 0, 0, 0);
            }
        __builtin_amdgcn_s_setprio(0);
        BARX();

        // q3: stage t+2 A (A reads done in q0/q2); tile-boundary counted wait
        if (pref) {
#pragma unroll
            for (int s = 0; s < SA; ++s) stageA(t + 2, s);
        }
        BARX();
        __builtin_amdgcn_s_setprio(1);
#pragma unroll
        for (int i = 0; i < MI / 2; ++i)
#pragma unroll
            for (int j = 0; j < 2; ++j) {
                acc[MI / 2 + i][j] = MFMA16(af[i][0], bfr[j][0], acc[MI / 2 + i][j], 0, 0, 0);
                acc[MI / 2 + i][j] = MFMA16(af[i][1], bfr[j][1], acc[MI / 2 + i][j], 0, 0, 0);
            }
        __builtin_amdgcn_s_setprio(0);
        if (pref)      VMW();                                     // t+1 resident; t+2 in flight
        else if (t + 1 < nt) asm volatile("s_waitcnt vmcnt(0)" ::: "memory");
        BARX();
    };

    for (int t = 0; t < nt; t += 2) { ktile(t); ktile(t + 1); }

    // ---- epilogue: D frag = 4 consecutive M rows (lh*4+r), N col = l15 ----
    if constexpr (MODE == 0) {
        const int sel = m0 >> 10;                 // 0:Q 1:K 2:V (uniform per block)
        const int eb  = (m0 & 1023) + wm * (BM / 2);
        if (sel < 2) {
            bf16* out = sel == 0 ? (bf16*)o0 : (bf16*)o1;
            const float* bias = sel == 0 ? bqp : bkp;
#pragma unroll
            for (int i = 0; i < MI; ++i) {
                int e0 = eb + i * 16 + lr4;
                float4 bb = *(const float4*)(bias + e0);
#pragma unroll
                for (int j = 0; j < 4; ++j) {
                    int l = n0 + wn * 64 + j * 16 + l15;
                    bf16x4 v = { (bf16)(acc[i][j][0] + bb.x), (bf16)(acc[i][j][1] + bb.y),
                                 (bf16)(acc[i][j][2] + bb.z), (bf16)(acc[i][j][3] + bb.w) };
                    *(bf16x4*)((bf16*)out + (size_t)l * DIM + e0) = v;
                }
            }
        } else {
            bf16* Vt = (bf16*)o2;
#pragma unroll
            for (int i = 0; i < MI; ++i) {
                int e0 = eb + i * 16 + lr4;
                float4 bb = *(const float4*)(bvp + e0);
                float bbr[4] = { bb.x, bb.y, bb.z, bb.w };
#pragma unroll
                for (int j = 0; j < 4; ++j) {
                    int lg = n0 + wn * 64 + j * 16 + l15;
                    int b = lg >> 11, l = lg & 2047;
#pragma unroll
                    for (int r = 0; r < 4; ++r)
                        Vt[((size_t)b * DIM + e0 + r) * L_SEQ + l] = (bf16)(acc[i][j][r] + bbr[r]);
                }
            }
        }
    } else if constexpr (MODE == 2) {
        float* sc = (float*)o0 + (size_t)z * L_SEQ * L_SEQ;
#pragma unroll
        for (int i = 0; i < MI; ++i) {
            int k0e = m0 + wm * (BM / 2) + i * 16 + lr4;
#pragma unroll
            for (int j = 0; j < 4; ++j) {
                int q = n0 + wn * 64 + j * 16 + l15;
                f32x4 v = acc[i][j] * 0.03125f;
                *(f32x4*)(sc + (size_t)q * L_SEQ + k0e) = v;
            }
        }
    } else {
        float* o = (float*)o0 + (size_t)z * L_SEQ * DIM;
#pragma unroll
        for (int i = 0; i < MI; ++i) {
            int e0 = m0 + wm * (BM / 2) + i * 16 + lr4;
#pragma unroll
            for (int j = 0; j < 4; ++j) {
                int q = n0 + wn * 64 + j * 16 + l15;
                *(f32x4*)(o + (size_t)q * DIM + e0) = acc[i][j];
            }
        }
    }
#undef VMW
}

// ---------------- causal row softmax: wts fp32 (in-place) + bf16 copy ----------------
__global__ __launch_bounds__(256)
void softmax_rows(float* __restrict__ wts, bf16* __restrict__ Pb)
{
    const int row = blockIdx.x;                 // 0..8191
    const int q = row & 2047;
    float* s = wts + (size_t)row * L_SEQ;
    bf16*  p = Pb  + (size_t)row * L_SEQ;
    const int t = threadIdx.x;
    const int lane = t & 63, w = t >> 6;
    const int k0 = t * 8;

    float v[8];
    if (k0 + 7 <= q) {
        float4 a = *(const float4*)(s + k0);
        float4 b = *(const float4*)(s + k0 + 4);
        v[0]=a.x; v[1]=a.y; v[2]=a.z; v[3]=a.w;
        v[4]=b.x; v[5]=b.y; v[6]=b.z; v[7]=b.w;
    } else {
#pragma unroll
        for (int c = 0; c < 8; ++c) {
            int k = k0 + c;
            v[c] = (k <= q) ? s[k] : -3.0e38f;
        }
    }

    float mx = v[0];
#pragma unroll
    for (int c = 1; c < 8; ++c) mx = fmaxf(mx, v[c]);
#pragma unroll
    for (int off = 32; off; off >>= 1) mx = fmaxf(mx, __shfl_xor(mx, off));
    __shared__ float redm[4];
    if (lane == 0) redm[w] = mx;
    __syncthreads();
    mx = fmaxf(fmaxf(redm[0], redm[1]), fmaxf(redm[2], redm[3]));

    float sm = 0.f;
#pragma unroll
    for (int c = 0; c < 8; ++c) {
        float e = __expf(v[c] - mx);             // masked -> 0 exactly
        v[c] = e;
        sm += e;
    }
#pragma unroll
    for (int off = 32; off; off >>= 1) sm += __shfl_xor(sm, off);
    __shared__ float reds[4];
    if (lane == 0) reds[w] = sm;
    __syncthreads();
    sm = reds[0] + reds[1] + reds[2] + reds[3];
    const float inv = 1.f / sm;

    if (k0 <= (q | 255)) {                       // beyond diag tile: pre-zeroed, PV never reads
        float o[8];
#pragma unroll
        for (int c = 0; c < 8; ++c) o[c] = v[c] * inv;
        float4 s0 = { o[0], o[1], o[2], o[3] };
        float4 s1 = { o[4], o[5], o[6], o[7] };
        *(float4*)(s + k0)     = s0;
        *(float4*)(s + k0 + 4) = s1;
        bf16x8 pb = { (bf16)o[0], (bf16)o[1], (bf16)o[2], (bf16)o[3],
                      (bf16)o[4], (bf16)o[5], (bf16)o[6], (bf16)o[7] };
        *(bf16x8*)(p + k0) = pb;
    }
}

extern "C" void kernel_launch(void* const* d_in, const int* in_sizes, int n_in,
                              void* d_out, int out_size, void* d_ws, size_t ws_size,
                              hipStream_t stream)
{
    const float* x  = (const float*)d_in[0];
    const float* Wq = (const float*)d_in[1];
    const float* bq = (const float*)d_in[2];
    const float* Wk = (const float*)d_in[3];
    const float* bk = (const float*)d_in[4];
    const float* Wv = (const float*)d_in[5];
    const float* bv = (const float*)d_in[6];

    float* out = (float*)d_out;                               // [4][2048][1024]
    float* wts = out + (size_t)BATCH * L_SEQ * DIM;           // [4][2048][2048]

    char* ws = (char*)d_ws;
    bf16* Xb   = (bf16*)(ws + 0);                  // 16 MiB  [8192][1024]
    bf16* Wcat = (bf16*)(ws + (16u  << 20));       //  6 MiB  [3072][1024]
    bf16* Qb   = (bf16*)(ws + (22u  << 20));       // 16 MiB  [b][l][e]
    bf16* Kb   = (bf16*)(ws + (38u  << 20));       // 16 MiB  [b][l][e]
    bf16* Vt   = (bf16*)(ws + (54u  << 20));       // 16 MiB  [b][e][l]
    bf16* Pb   = (bf16*)(ws + (70u  << 20));       // 32 MiB  [b][q][k]

    cvt_all<<<dim3(11264), dim3(256), 0, stream>>>(x, Wq, Wk, Wv, Xb, Wcat);

    gemmX<0, 256, 256, 512, 2, 4><<<dim3(384, 1, 1), dim3(512), 0, stream>>>(
        Wcat, Xb, bq, bk, bv, Qb, Kb, Vt);
    gemmX<2, 128, 256, 512, 2, 4><<<dim3(128, 1, 4), dim3(512), 0, stream>>>(
        Kb, Qb, nullptr, nullptr, nullptr, wts, nullptr, nullptr);
    softmax_rows<<<dim3(8192), dim3(256), 0, stream>>>(wts, Pb);
    gemmX<3, 128, 128, 256, 2, 2><<<dim3(512, 1, 1), dim3(256), 0, stream>>>(
        Vt, Pb, nullptr, nullptr, nullptr, out, nullptr, nullptr);
}